// Round 9
// baseline (316.090 us; speedup 1.0000x reference)
//
#include <hip/hip_runtime.h>
#include <stdint.h>

// Problem constants
#define S_DIM 512
#define B_DIM 64
#define T_DIM 768
#define A_DIM 512
#define H1_DIM 768
#define H2_DIM 640
#define N_DIM (H1_DIM + H2_DIM)   // 1408 combined hidden cols
#define M_DIM (S_DIM * B_DIM)     // 32768 rows
#define K_DIM T_DIM               // 768
#define NSLOT 22                  // 11 n-tiles x 2 wave-columns

typedef short s16x8 __attribute__((ext_vector_type(8)));
typedef float f32x4 __attribute__((ext_vector_type(4)));

__device__ __forceinline__ unsigned short f2bf(float f) {
    unsigned u = __float_as_uint(f);
    u += 0x7fffu + ((u >> 16) & 1u);   // round-to-nearest-even
    return (unsigned short)(u >> 16);
}

// --- fused prep: convA | convW | bias GEMV (all independent of each other) ---
#define CONVA_BLKS (M_DIM * K_DIM / 1024)            // 12288
#define CONVW_BLKS (N_DIM * K_DIM / 256)             // 4224
#define BIAS_BLKS  (22 * B_DIM)                      // 1408

__global__ __launch_bounds__(256) void prep_kernel(const float* __restrict__ ts,
                                                   const float* __restrict__ text,
                                                   const float* __restrict__ anp,
                                                   const float* __restrict__ W11,
                                                   const float* __restrict__ b11,
                                                   const float* __restrict__ W12,
                                                   const float* __restrict__ b12,
                                                   unsigned short* __restrict__ Abf,
                                                   unsigned short* __restrict__ Bt,
                                                   float* __restrict__ cbias) {
    const int blk = blockIdx.x;
    __shared__ float red[256];
    if (blk < CONVA_BLKS) {
        // convert text_seq fp32 -> bf16 (flat (M,K)), one float4 per thread
        int i = blk * 256 + threadIdx.x;
        float4 v = ((const float4*)ts)[i];
        ushort4 o;
        o.x = f2bf(v.x); o.y = f2bf(v.y); o.z = f2bf(v.z); o.w = f2bf(v.w);
        ((ushort4*)Abf)[i] = o;
    } else if (blk < CONVA_BLKS + CONVW_BLKS) {
        // build combined B^T bf16: Bt[n][k]
        int e = (blk - CONVA_BLKS) * 256 + threadIdx.x;
        int n = e / K_DIM, k = e % K_DIM;
        float v = (n < H1_DIM) ? W11[k * H1_DIM + n] : W12[k * H2_DIM + (n - H1_DIM)];
        Bt[e] = f2bf(v);
    } else {
        // bias: c[b][n] = x_b @ Wcol_n + bias_n, k-parallel tiled GEMV.
        // 256 thr = 64 n-lanes x 4 k-groups; W reads coalesced, x wave-uniform.
        const int t     = blk - CONVA_BLKS - CONVW_BLKS;   // 0..1407
        const int chunk = t % 22;                          // W-chunk fast: L2 reuse
        const int b     = t / 22;
        const int nl    = threadIdx.x & 63;
        const int kg    = threadIdx.x >> 6;
        float a0 = 0.f, a1 = 0.f;
        if (chunk < 12) {                        // h1: x=text (K=768)
            const int n = chunk * 64 + nl;
            const float* w = W11 + (size_t)T_DIM * H1_DIM + n;
            const float* x = text + b * T_DIM;
            for (int k = kg; k < T_DIM; k += 8) {
                a0 = fmaf(x[k],     w[(size_t)k * H1_DIM],       a0);
                a1 = fmaf(x[k + 4], w[(size_t)(k + 4) * H1_DIM], a1);
            }
        } else {                                 // h2: x=anp (K=512)
            const int n2 = (chunk - 12) * 64 + nl;
            const float* w = W12 + (size_t)T_DIM * H2_DIM + n2;
            const float* x = anp + b * A_DIM;
            for (int k = kg; k < A_DIM; k += 8) {
                a0 = fmaf(x[k],     w[(size_t)k * H2_DIM],       a0);
                a1 = fmaf(x[k + 4], w[(size_t)(k + 4) * H2_DIM], a1);
            }
        }
        red[kg * 64 + nl] = a0 + a1;
        __syncthreads();
        if (kg == 0) {
            const int n = chunk < 12 ? chunk * 64 + nl : H1_DIM + (chunk - 12) * 64 + nl;
            float base = (chunk < 12) ? b11[n] : b12[n - H1_DIM];
            cbias[b * N_DIM + n] =
                base + ((red[nl] + red[64 + nl]) + (red[128 + nl] + red[192 + nl]));
        }
    }
}

// --- main: bf16 MFMA GEMM with fused tanh-dot epilogue -> part [22][B][S] ---
// LDS chunk swizzle: logical chunk c (16B) of row r stored at chunk c^(r&7)
// via the global_load_lds SOURCE address; readers XOR the same way.
// XCD-aware block swizzle: xcd = lb&7, i = lb>>3, m = (i/11)*8 + xcd, n = i%11.
// Each XCD reuses its A-tiles 11x back-to-back (measured FETCH 135 -> 49 MB).
// launch_bounds (256,4): 64 VGPR + 64 AGPR = 128/wave -> 4 blocks/CU exactly.
#define BM 128
#define BN 128
#define BK 64

__global__ __launch_bounds__(256, 4) void gemm_score_kernel(
        const unsigned short* __restrict__ A,    // (M,K) bf16
        const unsigned short* __restrict__ Bt,   // (N,K) bf16
        const float* __restrict__ cbias,         // (B,N)
        const float* __restrict__ W21,           // (768)
        const float* __restrict__ W22,           // (640)
        float* __restrict__ part) {              // [22][B][S], one writer per slot
    __shared__ __align__(16) unsigned short As[BM * BK];   // 16 KB
    __shared__ __align__(16) unsigned short Bs[BN * BK];   // 16 KB
    const int tid  = threadIdx.x;
    const int lb   = blockIdx.x;
    const int xcd  = lb & 7;
    const int ib   = lb >> 3;                  // 0..351 per xcd
    const int m0   = ((ib / 11) * 8 + xcd) * BM;
    const int n0   = (ib % 11) * BN;
    const int lane = tid & 63;
    const int wave = tid >> 6;
    const int wm   = wave & 1;       // 2x2 waves over 128x128
    const int wn   = wave >> 1;
    const int quad = lane >> 4;
    const int col  = lane & 15;
    const int cswz = col & 7;        // row&7 == col&7 for fragment rows

    f32x4 acc[4][4] = {};            // 4x4 subtiles of 16x16 per wave

    // staging: each instr covers 8 rows x 64 k (1 KB contiguous LDS)
    const int wrow = lane >> 3;                        // 0..7 row within group
    const int kof  = (((lane & 7) ^ wrow) & 7) * 8;    // swizzled source chunk

    for (int k0 = 0; k0 < K_DIM; k0 += BK) {
        #pragma unroll
        for (int p = 0; p < 4; ++p) {
            const int r0 = p * 32 + wave * 8;    // wave-uniform row group (mult of 8)
            __builtin_amdgcn_global_load_lds(
                (__attribute__((address_space(1))) void*)&A[(size_t)(m0 + r0 + wrow) * K_DIM + k0 + kof],
                (__attribute__((address_space(3))) void*)&As[r0 * BK],
                16, 0, 0);
            __builtin_amdgcn_global_load_lds(
                (__attribute__((address_space(1))) void*)&Bt[(size_t)(n0 + r0 + wrow) * K_DIM + k0 + kof],
                (__attribute__((address_space(3))) void*)&Bs[r0 * BK],
                16, 0, 0);
        }
        __syncthreads();
        #pragma unroll
        for (int kk = 0; kk < BK; kk += 32) {
            s16x8 af[4], bf[4];
            const int ch = ((kk >> 3) + quad) ^ cswz;    // stored chunk index
            #pragma unroll
            for (int i = 0; i < 4; ++i)
                af[i] = *(const s16x8*)&As[(wm * 64 + i * 16 + col) * BK + ch * 8];
            #pragma unroll
            for (int j = 0; j < 4; ++j)
                bf[j] = *(const s16x8*)&Bs[(wn * 64 + j * 16 + col) * BK + ch * 8];
            #pragma unroll
            for (int i = 0; i < 4; ++i)
                #pragma unroll
                for (int j = 0; j < 4; ++j)
                    acc[i][j] = __builtin_amdgcn_mfma_f32_16x16x32_bf16(af[i], bf[j], acc[i][j], 0, 0, 0);
        }
        __syncthreads();
    }

    // Preload this block's cbias slice (64 b x 128 n_local = 32 KB) into LDS
    // (reusing As+Bs, safe after the final barrier), coalesced float4 loads.
    float* cb = (float*)As;          // cb[b][nl], nl = n - n0, 64x128
    {
        #pragma unroll
        for (int q = 0; q < 8; ++q) {
            int idx = q * 1024 + tid * 4;          // over 8192 floats
            int b   = idx >> 7, nl = idx & 127;
            *(float4*)&cb[idx] = *(const float4*)&cbias[b * N_DIM + n0 + nl];
        }
    }
    __syncthreads();

    // Epilogue: part[slot][b][s] = sum over this wave's 64 n-cols of
    // tanh(acc + c[b][n]) * w2[n].  slot = jb*2 + wn; unique writer per slot.
    const int half = (n0 >= H1_DIM) ? 1 : 0;     // tiles never straddle halves
    const int jb   = n0 >> 7;                    // 0..10
    const float* w2p = half ? (W22 - H1_DIM) : W21;
    int   nloc[4];
    float w2v[4];
    #pragma unroll
    for (int j = 0; j < 4; ++j) {
        nloc[j] = wn * 64 + j * 16 + col;
        w2v[j]  = w2p[n0 + nloc[j]];
    }
    float* pc = part + (jb * 2 + wn) * M_DIM;
    #pragma unroll
    for (int i = 0; i < 4; ++i) {
        #pragma unroll
        for (int r = 0; r < 4; ++r) {
            int row_local = wm * 64 + i * 16 + quad * 4 + r;   // C/D: row=quad*4+reg
            int b = row_local & (B_DIM - 1);                   // m0 % 128 == 0
            int s = (m0 + row_local) >> 6;
            float v = 0.f;
            #pragma unroll
            for (int j = 0; j < 4; ++j) {
                float pre = acc[i][j][r] + cb[b * 128 + nloc[j]];
                float ex  = __expf(2.f * pre);                 // tanh(x)=1-2/(e^{2x}+1)
                float th  = 1.f - 2.f * __builtin_amdgcn_rcpf(ex + 1.f);
                v = fmaf(th, w2v[j], v);
            }
            v += __shfl_xor(v, 1);    // reduce over the 16 cols (same quad = same row)
            v += __shfl_xor(v, 2);
            v += __shfl_xor(v, 4);
            v += __shfl_xor(v, 8);
            if (col == 0) pc[b * S_DIM + s] = v;
        }
    }
}

// --- softmax over S per (b, half) from 22 partials; wsum[b][s] = w1 + w2 ---
__global__ __launch_bounds__(512) void softmax_kernel(const float* __restrict__ part,
                                                      float* __restrict__ wsum) {
    const int b = blockIdx.x, s = threadIdx.x;   // 512 threads = 512 s
    __shared__ float redm[16], reds[16];
    float v0 = 0.f, v1 = 0.f;
    #pragma unroll
    for (int sl = 0; sl < 12; ++sl)       v0 += part[sl * M_DIM + b * S_DIM + s];
    #pragma unroll
    for (int sl = 12; sl < NSLOT; ++sl)   v1 += part[sl * M_DIM + b * S_DIM + s];
    float m0 = v0, m1 = v1;
    #pragma unroll
    for (int off = 32; off > 0; off >>= 1) {
        m0 = fmaxf(m0, __shfl_xor(m0, off));
        m1 = fmaxf(m1, __shfl_xor(m1, off));
    }
    const int w = s >> 6;
    if ((s & 63) == 0) { redm[w] = m0; redm[8 + w] = m1; }
    __syncthreads();
    m0 = redm[0]; m1 = redm[8];
    #pragma unroll
    for (int i = 1; i < 8; ++i) { m0 = fmaxf(m0, redm[i]); m1 = fmaxf(m1, redm[8 + i]); }
    float e0 = expf(v0 - m0), e1 = expf(v1 - m1);
    float s0 = e0, s1 = e1;
    #pragma unroll
    for (int off = 32; off > 0; off >>= 1) {
        s0 += __shfl_xor(s0, off);
        s1 += __shfl_xor(s1, off);
    }
    if ((s & 63) == 0) { reds[w] = s0; reds[8 + w] = s1; }
    __syncthreads();
    s0 = reds[0]; s1 = reds[8];
    #pragma unroll
    for (int i = 1; i < 8; ++i) { s0 += reds[i]; s1 += reds[8 + i]; }
    wsum[b * S_DIM + s] = e0 / s0 + e1 / s1;
}

// --- out[b,t] += (0.5/S) * sum_{s in chunk} wsum[b][s] * Abf[s,b,t] ---
// s-split x4 for occupancy (768 blocks); out pre-zeroed, atomicAdd combine.
__global__ __launch_bounds__(128) void wmean_kernel(const unsigned short* __restrict__ Abf,
                                                    const float* __restrict__ wsum,
                                                    float* __restrict__ out) {
    const int b  = blockIdx.x;
    const int tp = blockIdx.y * 128 + threadIdx.x;   // t-pair index 0..383
    const int s0 = blockIdx.z * 128;
    const unsigned short* base = Abf + (size_t)b * T_DIM + tp * 2;
    const float* wp = wsum + b * S_DIM;
    float a0 = 0.f, a1 = 0.f, c0 = 0.f, c1 = 0.f;
    #pragma unroll 4
    for (int s = s0; s < s0 + 128; s += 2) {
        float w0 = wp[s], w1 = wp[s + 1];
        unsigned u0 = *(const unsigned*)(base + (size_t)s * (B_DIM * T_DIM));
        unsigned u1 = *(const unsigned*)(base + (size_t)(s + 1) * (B_DIM * T_DIM));
        a0 = fmaf(w0, __uint_as_float(u0 << 16),          a0);
        a1 = fmaf(w0, __uint_as_float(u0 & 0xffff0000u),  a1);
        c0 = fmaf(w1, __uint_as_float(u1 << 16),          c0);
        c1 = fmaf(w1, __uint_as_float(u1 & 0xffff0000u),  c1);
    }
    atomicAdd(&out[b * T_DIM + tp * 2],     (a0 + c0) * (0.5f / (float)S_DIM));
    atomicAdd(&out[b * T_DIM + tp * 2 + 1], (a1 + c1) * (0.5f / (float)S_DIM));
}

extern "C" void kernel_launch(void* const* d_in, const int* in_sizes, int n_in,
                              void* d_out, int out_size, void* d_ws, size_t ws_size,
                              hipStream_t stream) {
    const float* text = (const float*)d_in[0];
    const float* anp  = (const float*)d_in[1];
    const float* ts   = (const float*)d_in[2];
    const float* W11  = (const float*)d_in[3];
    const float* b11  = (const float*)d_in[4];
    const float* W21  = (const float*)d_in[5];
    // d_in[6] = b21: unused, softmax is shift-invariant
    const float* W12  = (const float*)d_in[7];
    const float* b12  = (const float*)d_in[8];
    const float* W22  = (const float*)d_in[9];
    // d_in[10] = b22: unused
    float* out = (float*)d_out;

    // workspace layout (bytes): total ~55.9 MB
    char* ws = (char*)d_ws;
    unsigned short* Abf = (unsigned short*)ws;                                   // 50331648
    unsigned short* Bt  = (unsigned short*)(ws + 50331648);                      //  2162688
    float* cbias = (float*)(ws + 50331648 + 2162688);                            //   360448
    float* part  = (float*)(ws + 50331648 + 2162688 + 360448);                   //  2883584
    float* wsum  = (float*)(ws + 50331648 + 2162688 + 360448 + 2883584);         //   131072

    hipMemsetAsync(out, 0, B_DIM * T_DIM * sizeof(float), stream);
    prep_kernel<<<CONVA_BLKS + CONVW_BLKS + BIAS_BLKS, 256, 0, stream>>>(
        ts, text, anp, W11, b11, W12, b12, Abf, Bt, cbias);
    gemm_score_kernel<<<(M_DIM / BM) * (N_DIM / BN), 256, 0, stream>>>(
        Abf, Bt, cbias, W21, W22, part);
    softmax_kernel<<<B_DIM, 512, 0, stream>>>(part, wsum);
    wmean_kernel<<<dim3(B_DIM, 3, 4), 128, 0, stream>>>(Abf, wsum, out);
}

// Round 10
// 304.481 us; speedup vs baseline: 1.0381x; 1.0381x over previous
//
#include <hip/hip_runtime.h>
#include <stdint.h>

// Problem constants
#define S_DIM 512
#define B_DIM 64
#define T_DIM 768
#define A_DIM 512
#define H1_DIM 768
#define H2_DIM 640
#define N_DIM (H1_DIM + H2_DIM)   // 1408 combined hidden cols
#define M_DIM (S_DIM * B_DIM)     // 32768 rows
#define K_DIM T_DIM               // 768
#define NSLOT 22                  // 11 n-tiles x 2 wave-columns

typedef short s16x8 __attribute__((ext_vector_type(8)));
typedef float f32x4 __attribute__((ext_vector_type(4)));

__device__ __forceinline__ unsigned short f2bf(float f) {
    unsigned u = __float_as_uint(f);
    u += 0x7fffu + ((u >> 16) & 1u);   // round-to-nearest-even
    return (unsigned short)(u >> 16);
}

// --- fused prep: bias GEMV (first: latency overlaps the stream) | convW
// (LDS transpose, coalesced both sides) | convA (4 indep float4 per thread) ---
#define BIAS_BLKS  (22 * B_DIM)                      // 1408
#define CONVW_BLKS (22 * 12)                         // 264 (64x64 tiles)
#define CONVA_BLKS (M_DIM * K_DIM / 4 / 1024)        // 6144

__global__ __launch_bounds__(256) void prep_kernel(const float* __restrict__ ts,
                                                   const float* __restrict__ text,
                                                   const float* __restrict__ anp,
                                                   const float* __restrict__ W11,
                                                   const float* __restrict__ b11,
                                                   const float* __restrict__ W12,
                                                   const float* __restrict__ b12,
                                                   unsigned short* __restrict__ Abf,
                                                   unsigned short* __restrict__ Bt,
                                                   float* __restrict__ cbias) {
    const int blk = blockIdx.x;
    __shared__ float lds[64 * 65];         // transpose tile / bias reduce
    if (blk < BIAS_BLKS) {
        // bias: c[b][n] = x_b @ Wcol_n + bias_n, k-parallel tiled GEMV.
        const int chunk = blk % 22;                        // W-chunk fast: L2 reuse
        const int b     = blk / 22;
        const int nl    = threadIdx.x & 63;
        const int kg    = threadIdx.x >> 6;
        float a0 = 0.f, a1 = 0.f;
        if (chunk < 12) {                        // h1: x=text (K=768)
            const int n = chunk * 64 + nl;
            const float* w = W11 + (size_t)T_DIM * H1_DIM + n;
            const float* x = text + b * T_DIM;
            for (int k = kg; k < T_DIM; k += 8) {
                a0 = fmaf(x[k],     w[(size_t)k * H1_DIM],       a0);
                a1 = fmaf(x[k + 4], w[(size_t)(k + 4) * H1_DIM], a1);
            }
        } else {                                 // h2: x=anp (K=512)
            const int n2 = (chunk - 12) * 64 + nl;
            const float* w = W12 + (size_t)T_DIM * H2_DIM + n2;
            const float* x = anp + b * A_DIM;
            for (int k = kg; k < A_DIM; k += 8) {
                a0 = fmaf(x[k],     w[(size_t)k * H2_DIM],       a0);
                a1 = fmaf(x[k + 4], w[(size_t)(k + 4) * H2_DIM], a1);
            }
        }
        lds[kg * 64 + nl] = a0 + a1;
        __syncthreads();
        if (kg == 0) {
            const int n = chunk < 12 ? chunk * 64 + nl : H1_DIM + (chunk - 12) * 64 + nl;
            float base = (chunk < 12) ? b11[n] : b12[n - H1_DIM];
            cbias[b * N_DIM + n] =
                base + ((lds[nl] + lds[64 + nl]) + (lds[128 + nl] + lds[192 + nl]));
        }
    } else if (blk < BIAS_BLKS + CONVW_BLKS) {
        // convW: Bt[n][k] = bf16(W[k][n]) via 64x64 LDS transpose tile.
        const int t  = blk - BIAS_BLKS;
        const int nt = t / 12, kt = t % 12;          // n-tile 0..21, k-tile 0..11
        const int n0 = nt * 64, k0 = kt * 64;
        const int lo = threadIdx.x & 63;             // fast index
        const int hi = threadIdx.x >> 6;             // 0..3
        const float* Wp;  int ld;
        if (nt < 12) { Wp = W11 + n0;            ld = H1_DIM; }
        else         { Wp = W12 + (n0 - H1_DIM); ld = H2_DIM; }
        // read: lanes = consecutive n (coalesced 256B); k = hi*16 + r
        #pragma unroll
        for (int r = 0; r < 16; ++r) {
            int kl = hi * 16 + r;
            lds[kl * 65 + lo] = Wp[(size_t)(k0 + kl) * ld + lo];
        }
        __syncthreads();
        // write: lanes = consecutive k (coalesced 128B); LDS read stride 65
        // (65 % 32 == 1 -> 2-way bank alias, free)
        #pragma unroll
        for (int r = 0; r < 16; ++r) {
            int nl = hi * 16 + r;
            Bt[(size_t)(n0 + nl) * K_DIM + k0 + lo] = f2bf(lds[lo * 65 + nl]);
        }
    } else {
        // convA: text_seq fp32 -> bf16, 4 independent float4 loads per thread
        int i0 = (blk - BIAS_BLKS - CONVW_BLKS) * 1024 + threadIdx.x;
        float4 v0 = ((const float4*)ts)[i0];
        float4 v1 = ((const float4*)ts)[i0 + 256];
        float4 v2 = ((const float4*)ts)[i0 + 512];
        float4 v3 = ((const float4*)ts)[i0 + 768];
        ushort4 o0, o1, o2, o3;
        o0.x = f2bf(v0.x); o0.y = f2bf(v0.y); o0.z = f2bf(v0.z); o0.w = f2bf(v0.w);
        o1.x = f2bf(v1.x); o1.y = f2bf(v1.y); o1.z = f2bf(v1.z); o1.w = f2bf(v1.w);
        o2.x = f2bf(v2.x); o2.y = f2bf(v2.y); o2.z = f2bf(v2.z); o2.w = f2bf(v2.w);
        o3.x = f2bf(v3.x); o3.y = f2bf(v3.y); o3.z = f2bf(v3.z); o3.w = f2bf(v3.w);
        ((ushort4*)Abf)[i0]       = o0;
        ((ushort4*)Abf)[i0 + 256] = o1;
        ((ushort4*)Abf)[i0 + 512] = o2;
        ((ushort4*)Abf)[i0 + 768] = o3;
    }
}

// --- main: bf16 MFMA GEMM with fused tanh-dot epilogue -> part [22][B][S] ---
// LDS chunk swizzle: logical chunk c (16B) of row r stored at chunk c^(r&7)
// via the global_load_lds SOURCE address; readers XOR the same way.
// XCD-aware block swizzle: xcd = lb&7, i = lb>>3, m = (i/11)*8 + xcd, n = i%11.
// Each XCD reuses its A-tiles 11x back-to-back (measured FETCH 135 -> 49 MB).
#define BM 128
#define BN 128
#define BK 64

__global__ __launch_bounds__(256, 3) void gemm_score_kernel(
        const unsigned short* __restrict__ A,    // (M,K) bf16
        const unsigned short* __restrict__ Bt,   // (N,K) bf16
        const float* __restrict__ cbias,         // (B,N)
        const float* __restrict__ W21,           // (768)
        const float* __restrict__ W22,           // (640)
        float* __restrict__ part) {              // [22][B][S], one writer per slot
    __shared__ __align__(16) unsigned short As[BM * BK];   // 16 KB
    __shared__ __align__(16) unsigned short Bs[BN * BK];   // 16 KB
    const int tid  = threadIdx.x;
    const int lb   = blockIdx.x;
    const int xcd  = lb & 7;
    const int ib   = lb >> 3;                  // 0..351 per xcd
    const int m0   = ((ib / 11) * 8 + xcd) * BM;
    const int n0   = (ib % 11) * BN;
    const int lane = tid & 63;
    const int wave = tid >> 6;
    const int wm   = wave & 1;       // 2x2 waves over 128x128
    const int wn   = wave >> 1;
    const int quad = lane >> 4;
    const int col  = lane & 15;
    const int cswz = col & 7;        // row&7 == col&7 for fragment rows

    f32x4 acc[4][4] = {};            // 4x4 subtiles of 16x16 per wave

    // staging: each instr covers 8 rows x 64 k (1 KB contiguous LDS)
    const int wrow = lane >> 3;                        // 0..7 row within group
    const int kof  = (((lane & 7) ^ wrow) & 7) * 8;    // swizzled source chunk

    for (int k0 = 0; k0 < K_DIM; k0 += BK) {
        #pragma unroll
        for (int p = 0; p < 4; ++p) {
            const int r0 = p * 32 + wave * 8;    // wave-uniform row group (mult of 8)
            __builtin_amdgcn_global_load_lds(
                (__attribute__((address_space(1))) void*)&A[(size_t)(m0 + r0 + wrow) * K_DIM + k0 + kof],
                (__attribute__((address_space(3))) void*)&As[r0 * BK],
                16, 0, 0);
            __builtin_amdgcn_global_load_lds(
                (__attribute__((address_space(1))) void*)&Bt[(size_t)(n0 + r0 + wrow) * K_DIM + k0 + kof],
                (__attribute__((address_space(3))) void*)&Bs[r0 * BK],
                16, 0, 0);
        }
        __syncthreads();
        #pragma unroll
        for (int kk = 0; kk < BK; kk += 32) {
            s16x8 af[4], bf[4];
            const int ch = ((kk >> 3) + quad) ^ cswz;    // stored chunk index
            #pragma unroll
            for (int i = 0; i < 4; ++i)
                af[i] = *(const s16x8*)&As[(wm * 64 + i * 16 + col) * BK + ch * 8];
            #pragma unroll
            for (int j = 0; j < 4; ++j)
                bf[j] = *(const s16x8*)&Bs[(wn * 64 + j * 16 + col) * BK + ch * 8];
            #pragma unroll
            for (int i = 0; i < 4; ++i)
                #pragma unroll
                for (int j = 0; j < 4; ++j)
                    acc[i][j] = __builtin_amdgcn_mfma_f32_16x16x32_bf16(af[i], bf[j], acc[i][j], 0, 0, 0);
        }
        __syncthreads();
    }

    // Epilogue: part[slot][b][s] = sum over this wave's 64 n-cols of
    // tanh(acc + c[b][n]) * w2[n].  slot = jb*2 + wn; unique writer per slot.
    const int half = (n0 >= H1_DIM) ? 1 : 0;     // tiles never straddle halves
    const int jb   = n0 >> 7;                    // 0..10
    const float* w2p = half ? (W22 - H1_DIM) : W21;
    int   ncol[4];
    float w2v[4];
    #pragma unroll
    for (int j = 0; j < 4; ++j) {
        ncol[j] = n0 + wn * 64 + j * 16 + col;
        w2v[j]  = w2p[ncol[j]];
    }
    float* pc = part + (jb * 2 + wn) * M_DIM;
    #pragma unroll
    for (int i = 0; i < 4; ++i) {
        #pragma unroll
        for (int r = 0; r < 4; ++r) {
            int row_local = wm * 64 + i * 16 + quad * 4 + r;   // C/D: row=quad*4+reg
            int b = row_local & (B_DIM - 1);                   // m0 % 128 == 0
            int s = (m0 + row_local) >> 6;
            float v = 0.f;
            #pragma unroll
            for (int j = 0; j < 4; ++j) {
                float pre = acc[i][j][r] + cbias[b * N_DIM + ncol[j]];
                float ex  = __expf(2.f * pre);                 // tanh(x)=1-2/(e^{2x}+1)
                float th  = 1.f - 2.f * __builtin_amdgcn_rcpf(ex + 1.f);
                v = fmaf(th, w2v[j], v);
            }
            v += __shfl_xor(v, 1);    // reduce over the 16 cols (same quad = same row)
            v += __shfl_xor(v, 2);
            v += __shfl_xor(v, 4);
            v += __shfl_xor(v, 8);
            if (col == 0) pc[b * S_DIM + s] = v;
        }
    }
}

// --- softmax over S per (b, half) from 22 partials; wsum[b][s] = w1 + w2 ---
__global__ __launch_bounds__(512) void softmax_kernel(const float* __restrict__ part,
                                                      float* __restrict__ wsum) {
    const int b = blockIdx.x, s = threadIdx.x;   // 512 threads = 512 s
    __shared__ float redm[16], reds[16];
    float v0 = 0.f, v1 = 0.f;
    #pragma unroll
    for (int sl = 0; sl < 12; ++sl)       v0 += part[sl * M_DIM + b * S_DIM + s];
    #pragma unroll
    for (int sl = 12; sl < NSLOT; ++sl)   v1 += part[sl * M_DIM + b * S_DIM + s];
    float m0 = v0, m1 = v1;
    #pragma unroll
    for (int off = 32; off > 0; off >>= 1) {
        m0 = fmaxf(m0, __shfl_xor(m0, off));
        m1 = fmaxf(m1, __shfl_xor(m1, off));
    }
    const int w = s >> 6;
    if ((s & 63) == 0) { redm[w] = m0; redm[8 + w] = m1; }
    __syncthreads();
    m0 = redm[0]; m1 = redm[8];
    #pragma unroll
    for (int i = 1; i < 8; ++i) { m0 = fmaxf(m0, redm[i]); m1 = fmaxf(m1, redm[8 + i]); }
    float e0 = expf(v0 - m0), e1 = expf(v1 - m1);
    float s0 = e0, s1 = e1;
    #pragma unroll
    for (int off = 32; off > 0; off >>= 1) {
        s0 += __shfl_xor(s0, off);
        s1 += __shfl_xor(s1, off);
    }
    if ((s & 63) == 0) { reds[w] = s0; reds[8 + w] = s1; }
    __syncthreads();
    s0 = reds[0]; s1 = reds[8];
    #pragma unroll
    for (int i = 1; i < 8; ++i) { s0 += reds[i]; s1 += reds[8 + i]; }
    wsum[b * S_DIM + s] = e0 / s0 + e1 / s1;
}

// --- out[b,t] += (0.5/S) * sum_{s in chunk} wsum[b][s] * Abf[s,b,t] ---
// s-split x4 for occupancy (768 blocks); out pre-zeroed, atomicAdd combine.
__global__ __launch_bounds__(128) void wmean_kernel(const unsigned short* __restrict__ Abf,
                                                    const float* __restrict__ wsum,
                                                    float* __restrict__ out) {
    const int b  = blockIdx.x;
    const int tp = blockIdx.y * 128 + threadIdx.x;   // t-pair index 0..383
    const int s0 = blockIdx.z * 128;
    const unsigned short* base = Abf + (size_t)b * T_DIM + tp * 2;
    const float* wp = wsum + b * S_DIM;
    float a0 = 0.f, a1 = 0.f, c0 = 0.f, c1 = 0.f;
    #pragma unroll 4
    for (int s = s0; s < s0 + 128; s += 2) {
        float w0 = wp[s], w1 = wp[s + 1];
        unsigned u0 = *(const unsigned*)(base + (size_t)s * (B_DIM * T_DIM));
        unsigned u1 = *(const unsigned*)(base + (size_t)(s + 1) * (B_DIM * T_DIM));
        a0 = fmaf(w0, __uint_as_float(u0 << 16),          a0);
        a1 = fmaf(w0, __uint_as_float(u0 & 0xffff0000u),  a1);
        c0 = fmaf(w1, __uint_as_float(u1 << 16),          c0);
        c1 = fmaf(w1, __uint_as_float(u1 & 0xffff0000u),  c1);
    }
    atomicAdd(&out[b * T_DIM + tp * 2],     (a0 + c0) * (0.5f / (float)S_DIM));
    atomicAdd(&out[b * T_DIM + tp * 2 + 1], (a1 + c1) * (0.5f / (float)S_DIM));
}

extern "C" void kernel_launch(void* const* d_in, const int* in_sizes, int n_in,
                              void* d_out, int out_size, void* d_ws, size_t ws_size,
                              hipStream_t stream) {
    const float* text = (const float*)d_in[0];
    const float* anp  = (const float*)d_in[1];
    const float* ts   = (const float*)d_in[2];
    const float* W11  = (const float*)d_in[3];
    const float* b11  = (const float*)d_in[4];
    const float* W21  = (const float*)d_in[5];
    // d_in[6] = b21: unused, softmax is shift-invariant
    const float* W12  = (const float*)d_in[7];
    const float* b12  = (const float*)d_in[8];
    const float* W22  = (const float*)d_in[9];
    // d_in[10] = b22: unused
    float* out = (float*)d_out;

    // workspace layout (bytes): total ~55.9 MB
    char* ws = (char*)d_ws;
    unsigned short* Abf = (unsigned short*)ws;                                   // 50331648
    unsigned short* Bt  = (unsigned short*)(ws + 50331648);                      //  2162688
    float* cbias = (float*)(ws + 50331648 + 2162688);                            //   360448
    float* part  = (float*)(ws + 50331648 + 2162688 + 360448);                   //  2883584
    float* wsum  = (float*)(ws + 50331648 + 2162688 + 360448 + 2883584);         //   131072

    hipMemsetAsync(out, 0, B_DIM * T_DIM * sizeof(float), stream);
    prep_kernel<<<BIAS_BLKS + CONVW_BLKS + CONVA_BLKS, 256, 0, stream>>>(
        ts, text, anp, W11, b11, W12, b12, Abf, Bt, cbias);
    gemm_score_kernel<<<(M_DIM / BM) * (N_DIM / BN), 256, 0, stream>>>(
        Abf, Bt, cbias, W21, W22, part);
    softmax_kernel<<<B_DIM, 512, 0, stream>>>(part, wsum);
    wmean_kernel<<<dim3(B_DIM, 3, 4), 128, 0, stream>>>(Abf, wsum, out);
}